// Round 7
// baseline (209.402 us; speedup 1.0000x reference)
//
#include <hip/hip_runtime.h>
#include <hip/hip_bf16.h>

#define BB 2
#define TT 2048
#define DMM 1024
#define HH 16
#define HDD 64

typedef __attribute__((ext_vector_type(8))) short bf16x8;
typedef __attribute__((ext_vector_type(4))) short short4v;
typedef __attribute__((ext_vector_type(4))) float f32x4;

static __device__ __forceinline__ short f2bf(float f) {
    __hip_bfloat16 h = __float2bfloat16(f);
    return *reinterpret_cast<short*>(&h);
}

// ---- hidden f32 -> bf16 (4 elems/thread) ----
__global__ void cvt_hidden(const float* __restrict__ x, short* __restrict__ y) {
    int i = blockIdx.x * 256 + threadIdx.x;          // 1M threads, 4M elems
    float4 v = reinterpret_cast<const float4*>(x)[i];
    short4v o;
    o[0] = f2bf(v.x); o[1] = f2bf(v.y); o[2] = f2bf(v.z); o[3] = f2bf(v.w);
    reinterpret_cast<short4v*>(y)[i] = o;
}

// ---- W_eff = W + 2.0 * B@A  (or plain W), cast bf16 ----
__global__ void prep_w(const float* __restrict__ W, const float* __restrict__ A,
                       const float* __restrict__ Bm, short* __restrict__ outp, int lora) {
    int idx = blockIdx.x * 256 + threadIdx.x;        // 1M elems
    int n = idx >> 10, k = idx & 1023;
    float v = W[idx];
    if (lora) {
        float s = 0.f;
#pragma unroll
        for (int r = 0; r < 8; ++r) s += Bm[n * 8 + r] * A[r * 1024 + k];
        v += 2.0f * s;
    }
    outp[idx] = f2bf(v);
}

// ---- projection GEMM: C[m,n] = X[m,:] . W[n,:]  (both row-major, K contiguous) ----
// z = 0: Q (scale 0.125, layout [b][h][t][d]); z=1: K (same layout); z=2: V -> [b][h][d][t]
__global__ __launch_bounds__(256) void proj_gemm(
        const short* __restrict__ Xbf,
        const short* __restrict__ Wq, const short* __restrict__ Wk, const short* __restrict__ Wv,
        const float* __restrict__ bq, const float* __restrict__ bk, const float* __restrict__ bv,
        short* __restrict__ Qb, short* __restrict__ Kb, short* __restrict__ Vtb) {
    __shared__ __align__(16) char As[128 * 128];     // 128 rows x 64 bf16 (128B), swizzled
    __shared__ __align__(16) char Bs[128 * 128];

    const int mode = blockIdx.z;
    const short* Wbf = (mode == 0) ? Wq : (mode == 1) ? Wk : Wv;
    const float* bias = (mode == 0) ? bq : (mode == 1) ? bk : bv;
    short* outp = (mode == 0) ? Qb : (mode == 1) ? Kb : Vtb;
    const float scale = (mode == 0) ? 0.125f : 1.0f;  // HD^-0.5 folded into Q

    const int tid = threadIdx.x;
    const int wave = tid >> 6, lane = tid & 63;
    const int l15 = lane & 15, l4 = lane >> 4;
    const int m0 = blockIdx.y * 128, n0 = blockIdx.x * 128;
    const int wm = (wave >> 1) * 64, wn = (wave & 1) * 64;

    const int srow = tid >> 1;            // staging row 0..127
    const int scc = (tid & 1) * 4;        // 16B-chunk base (of 8 per row)

    f32x4 acc[4][4] = {};

    for (int k0 = 0; k0 < 1024; k0 += 64) {
        __syncthreads();
#pragma unroll
        for (int c = 0; c < 4; ++c) {
            int cc = scc + c;
            uint4 va = *reinterpret_cast<const uint4*>(Xbf + (m0 + srow) * 1024 + k0 + cc * 8);
            *reinterpret_cast<uint4*>(As + ((srow * 128 + cc * 16) ^ ((srow & 7) << 4))) = va;
            uint4 vb = *reinterpret_cast<const uint4*>(Wbf + (n0 + srow) * 1024 + k0 + cc * 8);
            *reinterpret_cast<uint4*>(Bs + ((srow * 128 + cc * 16) ^ ((srow & 7) << 4))) = vb;
        }
        __syncthreads();
#pragma unroll
        for (int kk = 0; kk < 2; ++kk) {
            const int colb = kk * 64 + l4 * 16;
            bf16x8 af[4], bfr[4];
#pragma unroll
            for (int mi = 0; mi < 4; ++mi) {
                int rowa = wm + mi * 16 + l15;
                af[mi] = *reinterpret_cast<const bf16x8*>(As + ((rowa * 128 + colb) ^ ((rowa & 7) << 4)));
                int rowb = wn + mi * 16 + l15;
                bfr[mi] = *reinterpret_cast<const bf16x8*>(Bs + ((rowb * 128 + colb) ^ ((rowb & 7) << 4)));
            }
#pragma unroll
            for (int mi = 0; mi < 4; ++mi)
#pragma unroll
                for (int ni = 0; ni < 4; ++ni)
                    acc[mi][ni] = __builtin_amdgcn_mfma_f32_16x16x32_bf16(af[mi], bfr[ni], acc[mi][ni], 0, 0, 0);
        }
    }

    // epilogue: C row = (l>>4)*4 + r, col = l&15
#pragma unroll
    for (int mi = 0; mi < 4; ++mi)
#pragma unroll
        for (int ni = 0; ni < 4; ++ni) {
            int gn = n0 + wn + ni * 16 + l15;
            float bv = bias[gn];
            int h = gn >> 6, d = gn & 63;
#pragma unroll
            for (int r = 0; r < 4; ++r) {
                int gm = m0 + wm + mi * 16 + l4 * 4 + r;
                int b = gm >> 11, t = gm & 2047;
                float v = (acc[mi][ni][r] + bv) * scale;
                int off;
                if (mode == 2) off = ((b * 16 + h) * 64 + d) * 2048 + t;     // V transposed
                else           off = ((b * 16 + h) * 2048 + t) * 64 + d;
                outp[off] = f2bf(v);
            }
        }
}

// ---- flash attention v5: swapped-QK orientation, interleaved pair, KVBLK=32 ----
// S^T = mfma(K, Q): lane = one q-column (q = qbase + l15), k-slices in regs
// (k = kvb + sl*16 + l4*4 + r). Row-softmax = in-lane 8-reg tree + 2 shfls.
// m/l are per-lane scalars. P^T written as 2x ds_write_b64; PV = mfma(V^T, P^T)
// accumulating O^T (col=q, row=d). Same K/V/Q global loads as before.

#define LOADK32(dst, kvb_) do {                                                      \
    int _kb = (kvb_);                                                                \
    _Pragma("unroll")                                                                \
    for (int _sl = 0; _sl < 2; ++_sl) {                                              \
        dst[_sl][0] = *reinterpret_cast<const bf16x8*>(Kp + (_kb + _sl*16 + l15)*64 + l4*8);      \
        dst[_sl][1] = *reinterpret_cast<const bf16x8*>(Kp + (_kb + _sl*16 + l15)*64 + 32 + l4*8); \
    }                                                                                \
} while (0)

// swapped QK^T + online softmax for one 16-col q-tile vs current 32-key tile.
// M, L are per-lane scalars (state for q = QB + l15).
#define TILE_QKSM(QF0, QF1, OO, M, L, QB, PB) do {                                   \
    f32x4 s0 = {}, s1 = {};                                                          \
    s0 = __builtin_amdgcn_mfma_f32_16x16x32_bf16(cur[0][0], QF0, s0, 0, 0, 0);       \
    s0 = __builtin_amdgcn_mfma_f32_16x16x32_bf16(cur[0][1], QF1, s0, 0, 0, 0);       \
    s1 = __builtin_amdgcn_mfma_f32_16x16x32_bf16(cur[1][0], QF0, s1, 0, 0, 0);       \
    s1 = __builtin_amdgcn_mfma_f32_16x16x32_bf16(cur[1][1], QF1, s1, 0, 0, 0);       \
    float pr0[4], pr1[4];                                                            \
    if (kvb + 31 > (QB)) {                                                           \
        _Pragma("unroll")                                                            \
        for (int r = 0; r < 4; ++r) {                                                \
            float v0 = s0[r] + mv0[r];                                               \
            if (kvb + l4*4 + r > (QB) + l15) v0 = -1e30f;                            \
            pr0[r] = v0;                                                             \
            float v1 = s1[r] + mv1[r];                                               \
            if (kvb + 16 + l4*4 + r > (QB) + l15) v1 = -1e30f;                       \
            pr1[r] = v1;                                                             \
        }                                                                            \
    } else {                                                                         \
        _Pragma("unroll")                                                            \
        for (int r = 0; r < 4; ++r) { pr0[r] = s0[r] + mv0[r]; pr1[r] = s1[r] + mv1[r]; } \
    }                                                                                \
    float tm = fmaxf(fmaxf(fmaxf(pr0[0], pr0[1]), fmaxf(pr0[2], pr0[3])),            \
                     fmaxf(fmaxf(pr1[0], pr1[1]), fmaxf(pr1[2], pr1[3])));           \
    tm = fmaxf(tm, __shfl_xor(tm, 16));                                              \
    tm = fmaxf(tm, __shfl_xor(tm, 32));                                              \
    if (!__all(tm - (M) <= 8.0f)) {                                                  \
        float mn = fmaxf(M, tm);                                                     \
        float al = __expf((M) - mn);                                                 \
        M = mn; L *= al;                                                             \
        _Pragma("unroll")                                                            \
        for (int dt = 0; dt < 4; ++dt)                                               \
            _Pragma("unroll")                                                        \
            for (int r = 0; r < 4; ++r) OO[dt][r] *= al;                             \
    }                                                                                \
    _Pragma("unroll")                                                                \
    for (int r = 0; r < 4; ++r) { pr0[r] = __expf(pr0[r] - (M)); pr1[r] = __expf(pr1[r] - (M)); } \
    float ps = (pr0[0] + pr0[1]) + (pr0[2] + pr0[3])                                 \
             + (pr1[0] + pr1[1]) + (pr1[2] + pr1[3]);                                \
    ps += __shfl_xor(ps, 16);                                                        \
    ps += __shfl_xor(ps, 32);                                                        \
    L += ps;                                                                         \
    short4v w0, w1;                                                                  \
    _Pragma("unroll")                                                                \
    for (int r = 0; r < 4; ++r) { w0[r] = f2bf(pr0[r]); w1[r] = f2bf(pr1[r]); }      \
    *reinterpret_cast<short4v*>((PB) + l15*40 + l4*4)      = w0;                     \
    *reinterpret_cast<short4v*>((PB) + l15*40 + 16 + l4*4) = w1;                     \
} while (0)

#define TILE_PV(OO, PB) do {                                                         \
    bf16x8 pf = *reinterpret_cast<const bf16x8*>((PB) + l15*40 + l4*8);              \
    _Pragma("unroll")                                                                \
    for (int dt = 0; dt < 4; ++dt)                                                   \
        OO[dt] = __builtin_amdgcn_mfma_f32_16x16x32_bf16(vf[dt], pf, OO[dt], 0, 0, 0); \
} while (0)

#define STEP(CUR, NXT, KT) do {                                                      \
    bf16x8 (*cur)[2] = CUR;                                                          \
    const int kvb = (KT) << 5;                                                       \
    LOADK32(NXT, kvb + 32);                                                          \
    bf16x8 vf[4];                                                                    \
    _Pragma("unroll")                                                                \
    for (int dt = 0; dt < 4; ++dt)                                                   \
        vf[dt] = *reinterpret_cast<const bf16x8*>(Vp + (dt*16 + l15)*2048 + kvb + l4*8); \
    float4 mv0 = *reinterpret_cast<const float4*>(mp + kvb + l4*4);                  \
    float4 mv1 = *reinterpret_cast<const float4*>(mp + kvb + 16 + l4*4);             \
    const bool doB = (KT) < nktB;                                                    \
    TILE_QKSM(qfA0, qfA1, OA, mA, lA, qbaseA, pbA);                                  \
    if (doB) TILE_QKSM(qfB0, qfB1, OB, mB, lB, qbaseB, pbB);                         \
    asm volatile("s_waitcnt lgkmcnt(0)" ::: "memory");                               \
    TILE_PV(OA, pbA);                                                                \
    if (doB) TILE_PV(OB, pbB);                                                       \
} while (0)

__global__ __launch_bounds__(256) void attn(
        const short* __restrict__ Qb, const short* __restrict__ Kb,
        const short* __restrict__ Vt, const float* __restrict__ amask,
        float* __restrict__ outp) {
    __shared__ __align__(16) short pb[4][2][16 * 40];  // per-wave A/B P^T buffers (80B row stride)

    const int tid = threadIdx.x, wv = tid >> 6, lane = tid & 63;
    const int l15 = lane & 15, l4 = lane >> 4;
    // XCD-chunked swizzle: 512 blocks, HW id x -> work id (x%8)*64 + x/8
    const int wid = ((blockIdx.x & 7) << 6) + (blockIdx.x >> 3);
    const int w = wid * 4 + wv;
    const int bh = w >> 6;                           // 32 (b,h) x 64 waves
    const int i = w & 63;                            // pair index
    const int b = bh >> 4, h = bh & 15;

    const short* Qp = Qb + bh * TT * HDD;
    const short* Kp = Kb + bh * TT * HDD;
    const short* Vp = Vt + bh * HDD * TT;
    const float* mp = amask + b * TT;
    short* pbA = &pb[wv][0][0];
    short* pbB = &pb[wv][1][0];

    const int qbaseA = (127 - i) << 4;               // big tile
    const int qbaseB = i << 4;                       // small tile (kv range subset of A's)

    // B-operand Q fragments: col=q=l15, d elems l4*8+j (same loads as before)
    bf16x8 qfA0 = *reinterpret_cast<const bf16x8*>(Qp + (qbaseA + l15) * 64 + l4 * 8);
    bf16x8 qfA1 = *reinterpret_cast<const bf16x8*>(Qp + (qbaseA + l15) * 64 + 32 + l4 * 8);
    bf16x8 qfB0 = *reinterpret_cast<const bf16x8*>(Qp + (qbaseB + l15) * 64 + l4 * 8);
    bf16x8 qfB1 = *reinterpret_cast<const bf16x8*>(Qp + (qbaseB + l15) * 64 + 32 + l4 * 8);

    f32x4 OA[4] = {}, OB[4] = {};                    // O^T: col=q=l15, row=d
    float mA = -1e30f, mB = -1e30f;                  // per-lane scalars (q = qbase+l15)
    float lA = 0.f, lB = 0.f;

    const int nktA = (qbaseA + 47) >> 5;             // 32-wide kv tiles, causal bound
    const int nktB = (qbaseB + 47) >> 5;

    bf16x8 kfP[2][2], kfQ[2][2];
    LOADK32(kfP, 0);

    int kt = 0;
    while (1) {
        STEP(kfP, kfQ, kt);
        if (++kt >= nktA) break;
        STEP(kfQ, kfP, kt);
        if (++kt >= nktA) break;
    }

    // epilogue: lane holds q = qbase+l15, d = dt*16 + l4*4 + r  -> float4 stores
    {
        float invA = 1.0f / lA, invB = 1.0f / lB;
        int tA = qbaseA + l15, tB = qbaseB + l15;
#pragma unroll
        for (int dt = 0; dt < 4; ++dt) {
            float4 oa, ob;
            oa.x = OA[dt][0] * invA; oa.y = OA[dt][1] * invA;
            oa.z = OA[dt][2] * invA; oa.w = OA[dt][3] * invA;
            ob.x = OB[dt][0] * invB; ob.y = OB[dt][1] * invB;
            ob.z = OB[dt][2] * invB; ob.w = OB[dt][3] * invB;
            *reinterpret_cast<float4*>(outp + (b * 2048 + tA) * 1024 + h * 64 + dt * 16 + l4 * 4) = oa;
            *reinterpret_cast<float4*>(outp + (b * 2048 + tB) * 1024 + h * 64 + dt * 16 + l4 * 4) = ob;
        }
    }
}

extern "C" void kernel_launch(void* const* d_in, const int* in_sizes, int n_in,
                              void* d_out, int out_size, void* d_ws, size_t ws_size,
                              hipStream_t stream) {
    const float* hidden = (const float*)d_in[0];
    const float* amask  = (const float*)d_in[1];
    const float* Wq = (const float*)d_in[2];
    const float* bq = (const float*)d_in[3];
    const float* Aq = (const float*)d_in[4];
    const float* Bq = (const float*)d_in[5];
    const float* Wk = (const float*)d_in[6];
    const float* bk = (const float*)d_in[7];
    const float* Wv = (const float*)d_in[8];
    const float* bv = (const float*)d_in[9];
    const float* Av = (const float*)d_in[10];
    const float* Bv = (const float*)d_in[11];
    float* outp = (float*)d_out;

    char* ws = (char*)d_ws;
    short* Xbf = (short*)(ws);                 // 8 MB  [4096][1024] bf16
    short* Wqe = (short*)(ws + (8 << 20));     // 2 MB
    short* Wke = (short*)(ws + (10 << 20));    // 2 MB
    short* Wve = (short*)(ws + (12 << 20));    // 2 MB
    short* Qb  = (short*)(ws + (14 << 20));    // 8 MB  [b][h][t][d]
    short* Kb  = (short*)(ws + (22 << 20));    // 8 MB  [b][h][t][d]
    short* Vtb = (short*)(ws + (30 << 20));    // 8 MB  [b][h][d][t]

    cvt_hidden<<<4096, 256, 0, stream>>>(hidden, Xbf);
    prep_w<<<4096, 256, 0, stream>>>(Wq, Aq, Bq, Wqe, 1);
    prep_w<<<4096, 256, 0, stream>>>(Wk, nullptr, nullptr, Wke, 0);
    prep_w<<<4096, 256, 0, stream>>>(Wv, Av, Bv, Wve, 1);
    proj_gemm<<<dim3(8, 32, 3), 256, 0, stream>>>(Xbf, Wqe, Wke, Wve, bq, bk, bv, Qb, Kb, Vtb);
    attn<<<512, 256, 0, stream>>>(Qb, Kb, Vtb, amask, outp);
}